// Round 2
// baseline (524.715 us; speedup 1.0000x reference)
//
#include <hip/hip_runtime.h>
#include <stdint.h>

#define NTOK 4096   // B*S = 2*2048
#define DDIM 1024
#define HDIM 2048
#define NEXP 8
#define TOPK 2

typedef short bf16x8 __attribute__((ext_vector_type(8)));
typedef float f32x4 __attribute__((ext_vector_type(4)));

__device__ __forceinline__ unsigned short f2bf(float f) {
    union { float f; unsigned int u; } v; v.f = f;
    unsigned int r = v.u + 0x7fffu + ((v.u >> 16) & 1u);
    return (unsigned short)(r >> 16);
}

__device__ __forceinline__ void gload16(const void* g, void* l) {
    __builtin_amdgcn_global_load_lds(
        (const __attribute__((address_space(1))) unsigned int*)g,
        (__attribute__((address_space(3))) unsigned int*)l, 16, 0, 0);
}

// ---------------- gating: logits, top-2, gates, counts; also x -> bf16 ----------------
__global__ __launch_bounds__(256) void k_gate(
    const float* __restrict__ x, const float* __restrict__ gw,
    unsigned short* __restrict__ xb, int* __restrict__ cnt,
    int* __restrict__ topi, float* __restrict__ topg)
{
    int w = threadIdx.x >> 6, ln = threadIdx.x & 63;
    int n = blockIdx.x * 4 + w;
    const float* xr = x + (size_t)n * DDIM;
    float p[NEXP];
#pragma unroll
    for (int e = 0; e < NEXP; e++) p[e] = 0.f;
#pragma unroll
    for (int j = 0; j < DDIM / 64; j++) {
        int idx = ln + 64 * j;
        float xv = xr[idx];
        xb[(size_t)n * DDIM + idx] = f2bf(xv);
#pragma unroll
        for (int e = 0; e < NEXP; e++) p[e] += xv * gw[e * DDIM + idx];
    }
#pragma unroll
    for (int off = 32; off >= 1; off >>= 1) {
#pragma unroll
        for (int e = 0; e < NEXP; e++) p[e] += __shfl_xor(p[e], off, 64);
    }
    if (ln == 0) {
        int i0 = 0; float v0 = p[0];
#pragma unroll
        for (int e = 1; e < NEXP; e++) if (p[e] > v0) { v0 = p[e]; i0 = e; }
        int i1 = -1; float v1 = -3.0e38f;
#pragma unroll
        for (int e = 0; e < NEXP; e++) if (e != i0 && p[e] > v1) { v1 = p[e]; i1 = e; }
        float g0 = 1.f / (1.f + __expf(v1 - v0));  // softmax of [v0,v1], v0 >= v1
        float g1 = 1.f - g0;
        atomicAdd(&cnt[i0], 1); atomicAdd(&cnt[i1], 1);
        topi[n * 2] = i0; topi[n * 2 + 1] = i1;
        topg[n * 2] = g0; topg[n * 2 + 1] = g1;
    }
}

// ---------------- prefix-sum over expert counts + aux loss ----------------
__global__ void k_scan(const int* __restrict__ cnt, int* __restrict__ offs,
                       float* __restrict__ auxout)
{
    if (threadIdx.x == 0) {
        int o = 0; float aux = 0.f;
#pragma unroll
        for (int e = 0; e < NEXP; e++) {
            offs[e] = o; o += cnt[e];
            float l = (float)cnt[e] / (float)(NTOK * TOPK);
            aux += l * l;
        }
        offs[NEXP] = o;
        auxout[0] = 0.01f * (float)NEXP * aux;
    }
}

// ---------------- scatter token ids / gate weights into expert buckets ----------------
__global__ __launch_bounds__(256) void k_scatter(
    const int* __restrict__ topi, const float* __restrict__ topg,
    const int* __restrict__ offs, int* __restrict__ fill,
    int* __restrict__ tok, float* __restrict__ gate)
{
    int g = blockIdx.x * 256 + threadIdx.x;
    if (g >= NTOK * TOPK) return;
    int e = topi[g];
    int pos = atomicAdd(&fill[e], 1);
    int slot = offs[e] + pos;
    tok[slot] = g >> 1;
    gate[slot] = topg[g];
}

// ---------------- fp32 -> bf16 weight conversion ----------------
__global__ __launch_bounds__(256) void k_conv(
    const float4* __restrict__ w1, const float4* __restrict__ w2,
    ushort4* __restrict__ w1b, ushort4* __restrict__ w2b)
{
    const int t1 = NEXP * HDIM * DDIM / 4;   // 4,194,304 vec4
    int stride = gridDim.x * blockDim.x;
    for (int i = blockIdx.x * 256 + threadIdx.x; i < 2 * t1; i += stride) {
        float4 v = (i < t1) ? w1[i] : w2[i - t1];
        ushort4 o;
        o.x = f2bf(v.x); o.y = f2bf(v.y); o.z = f2bf(v.z); o.w = f2bf(v.w);
        if (i < t1) w1b[i] = o; else w2b[i - t1] = o;
    }
}

// ---------------- per-expert FFN GEMM (m97 structure: 128x128, BK=64, 4 waves) ----------
// FFN1: h = silu(Xe @ W1^T + b1)  (K=1024, N=2048), A gathered via tok list
// FFN2: out += gate * (h @ W2^T + b2) (K=2048, N=1024), A contiguous, atomic scatter-add
template<int KDIM, bool FFN1>
__global__ __launch_bounds__(256) void k_ffn(
    const unsigned short* __restrict__ Abase,
    const unsigned short* __restrict__ Wb,
    const float* __restrict__ bias,
    const int* __restrict__ offs,
    const int* __restrict__ tok,
    const float* __restrict__ gate,
    unsigned short* __restrict__ hbuf,
    float* __restrict__ out)
{
    constexpr int NCOLS = FFN1 ? HDIM : DDIM;
    int e = blockIdx.z;
    int soff = offs[e];
    int n_e = offs[e + 1] - soff;
    int row0 = blockIdx.y * 128;
    if (row0 >= n_e) return;
    int ncol0 = blockIdx.x * 128;

    __shared__ __align__(16) unsigned short As[128 * 64];
    __shared__ __align__(16) unsigned short Bs[128 * 64];

    int tid = threadIdx.x;
    int w = tid >> 6, ln = tid & 63;
    int wr = w >> 1, wc = w & 1;

    // per-issue A row pointers (gather hoisted out of K loop)
    const unsigned short* aptr[4];
#pragma unroll
    for (int i = 0; i < 4; i++) {
        int r = row0 + i * 32 + w * 8 + (ln >> 3);
        int rc = (r < n_e) ? r : (n_e - 1);
        size_t grow = FFN1 ? (size_t)tok[soff + rc] : (size_t)(soff + rc);
        aptr[i] = Abase + grow * KDIM + ((ln & 7) * 8);
    }
    const unsigned short* Wexp = Wb + (size_t)e * NCOLS * KDIM;
    const unsigned short* bptr[4];
#pragma unroll
    for (int i = 0; i < 4; i++) {
        int brow = ncol0 + i * 32 + w * 8 + (ln >> 3);
        bptr[i] = Wexp + (size_t)brow * KDIM + ((ln & 7) * 8);
    }

    f32x4 acc[4][4];
#pragma unroll
    for (int m = 0; m < 4; m++)
#pragma unroll
        for (int n = 0; n < 4; n++) acc[m][n] = (f32x4)0.f;

    int ln15 = ln & 15, kq = (ln >> 4) * 8;

    for (int k0 = 0; k0 < KDIM; k0 += 64) {
        __syncthreads();
#pragma unroll
        for (int i = 0; i < 4; i++) {
            int chunk = i * 4 + w;                 // wave-uniform
            gload16(aptr[i] + k0, &As[chunk * 512]);
            gload16(bptr[i] + k0, &Bs[chunk * 512]);
        }
        __syncthreads();
#pragma unroll
        for (int kk = 0; kk < 64; kk += 32) {
            bf16x8 af[4], bfr[4];
#pragma unroll
            for (int m = 0; m < 4; m++)
                af[m] = *(const bf16x8*)&As[(wr * 64 + m * 16 + ln15) * 64 + kk + kq];
#pragma unroll
            for (int n = 0; n < 4; n++)
                bfr[n] = *(const bf16x8*)&Bs[(wc * 64 + n * 16 + ln15) * 64 + kk + kq];
#pragma unroll
            for (int m = 0; m < 4; m++)
#pragma unroll
                for (int n = 0; n < 4; n++)
                    acc[m][n] = __builtin_amdgcn_mfma_f32_16x16x32_bf16(
                        af[m], bfr[n], acc[m][n], 0, 0, 0);
        }
    }

    int rowb = row0 + wr * 64;
    int colb = ncol0 + wc * 64;
    int r4 = (ln >> 4) * 4;
    if (FFN1) {
#pragma unroll
        for (int n = 0; n < 4; n++) {
            int col = colb + n * 16 + ln15;
            float bv = bias[e * NCOLS + col];
#pragma unroll
            for (int m = 0; m < 4; m++) {
#pragma unroll
                for (int q = 0; q < 4; q++) {
                    int r = rowb + m * 16 + r4 + q;
                    if (r < n_e) {
                        float v = acc[m][n][q] + bv;
                        float s = v / (1.f + __expf(-v));   // silu
                        hbuf[(size_t)(soff + r) * HDIM + col] = f2bf(s);
                    }
                }
            }
        }
    } else {
#pragma unroll
        for (int m = 0; m < 4; m++) {
            int rbase = rowb + m * 16 + r4;
            int tk[4]; float gt[4];
#pragma unroll
            for (int q = 0; q < 4; q++) {
                int r = rbase + q;
                int rc = (r < n_e) ? r : 0;
                tk[q] = tok[soff + rc];
                gt[q] = gate[soff + rc];
            }
#pragma unroll
            for (int n = 0; n < 4; n++) {
                int col = colb + n * 16 + ln15;
                float bv = bias[e * NCOLS + col];
#pragma unroll
                for (int q = 0; q < 4; q++) {
                    int r = rbase + q;
                    if (r < n_e) {
                        float v = gt[q] * (acc[m][n][q] + bv);
                        atomicAdd(&out[(size_t)tk[q] * DDIM + col], v);
                    }
                }
            }
        }
    }
}

extern "C" void kernel_launch(void* const* d_in, const int* in_sizes, int n_in,
                              void* d_out, int out_size, void* d_ws, size_t ws_size,
                              hipStream_t stream)
{
    const float* x  = (const float*)d_in[0];
    const float* gw = (const float*)d_in[1];
    const float* w1 = (const float*)d_in[2];
    const float* b1 = (const float*)d_in[3];
    const float* w2 = (const float*)d_in[4];
    const float* b2 = (const float*)d_in[5];
    float* out = (float*)d_out;

    char* ws = (char*)d_ws;
    size_t off = 0;
    auto alloc = [&](size_t bytes) {
        char* p = ws + off; off += (bytes + 255) & ~(size_t)255; return p;
    };
    unsigned short* xb  = (unsigned short*)alloc((size_t)NTOK * DDIM * 2);           // 8.4 MB
    unsigned short* w1b = (unsigned short*)alloc((size_t)NEXP * HDIM * DDIM * 2);    // 33.5 MB
    unsigned short* w2b = (unsigned short*)alloc((size_t)NEXP * DDIM * HDIM * 2);    // 33.5 MB
    unsigned short* hb  = (unsigned short*)alloc((size_t)NTOK * TOPK * HDIM * 2);    // 33.5 MB
    int*   tok  = (int*)alloc(NTOK * TOPK * 4);
    float* gate = (float*)alloc(NTOK * TOPK * 4);
    int*   topi = (int*)alloc(NTOK * TOPK * 4);
    float* topg = (float*)alloc(NTOK * TOPK * 4);
    int*   ctrl = (int*)alloc(256);   // ints: [0..7]=cnt, [16..24]=offs, [32..39]=fill

    int* cnt  = ctrl;
    int* offs = ctrl + 16;
    int* fill = ctrl + 32;

    hipMemsetAsync(ctrl, 0, 256, stream);
    hipMemsetAsync(d_out, 0, (size_t)out_size * sizeof(float), stream);

    k_gate<<<NTOK / 4, 256, 0, stream>>>(x, gw, xb, cnt, topi, topg);
    k_scan<<<1, 64, 0, stream>>>(cnt, offs, out + (size_t)NTOK * DDIM);
    k_scatter<<<(NTOK * TOPK) / 256, 256, 0, stream>>>(topi, topg, offs, fill, tok, gate);
    k_conv<<<2048, 256, 0, stream>>>((const float4*)w1, (const float4*)w2,
                                     (ushort4*)w1b, (ushort4*)w2b);
    // FFN1: grid (H/128, max_m_tiles, E); inactive tiles early-exit on device counts
    k_ffn<DDIM, true ><<<dim3(HDIM / 128, NTOK / 128, NEXP), 256, 0, stream>>>(
        xb, w1b, b1, offs, tok, gate, hb, out);
    // FFN2
    k_ffn<HDIM, false><<<dim3(DDIM / 128, NTOK / 128, NEXP), 256, 0, stream>>>(
        hb, w2b, b2, offs, tok, gate, hb, out);
}

// Round 3
// 479.322 us; speedup vs baseline: 1.0947x; 1.0947x over previous
//
#include <hip/hip_runtime.h>
#include <stdint.h>

#define NTOK 4096   // B*S = 2*2048
#define DDIM 1024
#define HDIM 2048
#define NEXP 8
#define TOPK 2

typedef short bf16x8 __attribute__((ext_vector_type(8)));
typedef float f32x4 __attribute__((ext_vector_type(4)));

__device__ __forceinline__ unsigned short f2bf(float f) {
    union { float f; unsigned int u; } v; v.f = f;
    unsigned int r = v.u + 0x7fffu + ((v.u >> 16) & 1u);
    return (unsigned short)(r >> 16);
}

__device__ __forceinline__ void gload16(const void* g, void* l) {
    __builtin_amdgcn_global_load_lds(
        (const __attribute__((address_space(1))) unsigned int*)g,
        (__attribute__((address_space(3))) unsigned int*)l, 16, 0, 0);
}

// ---------------- gating: logits, top-2, gates, counts; also x -> bf16 ----------------
__global__ __launch_bounds__(256) void k_gate(
    const float* __restrict__ x, const float* __restrict__ gw,
    unsigned short* __restrict__ xb, int* __restrict__ cnt,
    int* __restrict__ topi, float* __restrict__ topg)
{
    int w = threadIdx.x >> 6, ln = threadIdx.x & 63;
    int n = blockIdx.x * 4 + w;
    const float* xr = x + (size_t)n * DDIM;
    float p[NEXP];
#pragma unroll
    for (int e = 0; e < NEXP; e++) p[e] = 0.f;
#pragma unroll
    for (int j = 0; j < DDIM / 64; j++) {
        int idx = ln + 64 * j;
        float xv = xr[idx];
        xb[(size_t)n * DDIM + idx] = f2bf(xv);
#pragma unroll
        for (int e = 0; e < NEXP; e++) p[e] += xv * gw[e * DDIM + idx];
    }
#pragma unroll
    for (int off = 32; off >= 1; off >>= 1) {
#pragma unroll
        for (int e = 0; e < NEXP; e++) p[e] += __shfl_xor(p[e], off, 64);
    }
    if (ln == 0) {
        int i0 = 0; float v0 = p[0];
#pragma unroll
        for (int e = 1; e < NEXP; e++) if (p[e] > v0) { v0 = p[e]; i0 = e; }
        int i1 = -1; float v1 = -3.0e38f;
#pragma unroll
        for (int e = 0; e < NEXP; e++) if (e != i0 && p[e] > v1) { v1 = p[e]; i1 = e; }
        float g0 = 1.f / (1.f + __expf(v1 - v0));  // softmax of [v0,v1], v0 >= v1
        float g1 = 1.f - g0;
        atomicAdd(&cnt[i0], 1); atomicAdd(&cnt[i1], 1);
        topi[n * 2] = i0; topi[n * 2 + 1] = i1;
        topg[n * 2] = g0; topg[n * 2 + 1] = g1;
    }
}

// ---------------- prefix-sum over expert counts + aux loss ----------------
__global__ void k_scan(const int* __restrict__ cnt, int* __restrict__ offs,
                       float* __restrict__ auxout)
{
    if (threadIdx.x == 0) {
        int o = 0; float aux = 0.f;
#pragma unroll
        for (int e = 0; e < NEXP; e++) {
            offs[e] = o; o += cnt[e];
            float l = (float)cnt[e] / (float)(NTOK * TOPK);
            aux += l * l;
        }
        offs[NEXP] = o;
        auxout[0] = 0.01f * (float)NEXP * aux;
    }
}

// ---------------- scatter token ids / gate weights into expert buckets ----------------
__global__ __launch_bounds__(256) void k_scatter(
    const int* __restrict__ topi, const float* __restrict__ topg,
    const int* __restrict__ offs, int* __restrict__ fill,
    int* __restrict__ tok, float* __restrict__ gate)
{
    int g = blockIdx.x * 256 + threadIdx.x;
    if (g >= NTOK * TOPK) return;
    int e = topi[g];
    int pos = atomicAdd(&fill[e], 1);
    int slot = offs[e] + pos;
    tok[slot] = g >> 1;
    gate[slot] = topg[g];
}

// ---------------- fp32 -> bf16 weight conversion ----------------
__global__ __launch_bounds__(256) void k_conv(
    const float4* __restrict__ w1, const float4* __restrict__ w2,
    ushort4* __restrict__ w1b, ushort4* __restrict__ w2b)
{
    const int t1 = NEXP * HDIM * DDIM / 4;   // 4,194,304 vec4
    int stride = gridDim.x * blockDim.x;
    for (int i = blockIdx.x * 256 + threadIdx.x; i < 2 * t1; i += stride) {
        float4 v = (i < t1) ? w1[i] : w2[i - t1];
        ushort4 o;
        o.x = f2bf(v.x); o.y = f2bf(v.y); o.z = f2bf(v.z); o.w = f2bf(v.w);
        if (i < t1) w1b[i] = o; else w2b[i - t1] = o;
    }
}

// =====================================================================================
// 8-phase FFN GEMM: BM=128, BN=256, BK=64, 512 threads = 8 waves (2M x 4N).
// Per-wave output 64x64 = 4x4 frags of mfma_f32_16x16x32_bf16.
// LDS per buffer: A 2 chunks x 8KB + B 2 chunks x 16KB = 48KB; x2 dbuf = 96KB.
// Chunk row-permutation: A chunk c holds tile rows {wm*64 + c*32 + 0..31}; B likewise
// over out-cols. XOR swizzle: 16B-chunk index ^= (ldsrow & 7); applied on the global
// SOURCE address at stage time (LDS dest linear, required by global_load_lds) and on
// the ds_read index at consume time.
// Stage schedule per iter (tiles t even in buf0, t+1 in buf1; 3 chunks in flight):
//   P0:A1(t+1) P1:A0(t+2) P2:B0(t+2) P3:B1(t+2)+vmcnt(5) P4:A1(t+2) P5:A0(t+3)
//   P6:B0(t+3) P7:B1(t+3)+vmcnt(5).  Last iter: only P0's stage; vmcnt(0) at P3.
// =====================================================================================

#define VMCNT(n) asm volatile("s_waitcnt vmcnt(" #n ")" ::: "memory")
#define SBAR do { __builtin_amdgcn_sched_barrier(0); __builtin_amdgcn_s_barrier(); } while(0)
#define PRIO1 __builtin_amdgcn_s_setprio(1)
#define PRIO0 __builtin_amdgcn_s_setprio(0)

#define PH_STAGE_A(b,c,tt) gload16(aSrc[c] + (size_t)(tt)*64, smem + (b)*49152 + (c)*8192 + w*1024)
#define PH_STAGE_B(b,c,tt) do { \
    gload16(bSrc[c][0] + (size_t)(tt)*64, smem + (b)*49152 + 16384 + (c)*16384 + w*1024); \
    gload16(bSrc[c][1] + (size_t)(tt)*64, smem + (b)*49152 + 16384 + (c)*16384 + 8192 + w*1024); } while(0)

#define LDA_(b, mp) do { _Pragma("unroll") for (int mi=0;mi<2;mi++){ _Pragma("unroll") for(int k=0;k<2;k++){ \
    afr[mi][k] = *(const bf16x8*)(smem + (b)*49152 + (mp)*8192 + (wm*32 + mi*16 + ln15)*128 + colx[k]); }} } while(0)
#define LDB_(b, np, D) do { _Pragma("unroll") for (int ni=0;ni<2;ni++){ _Pragma("unroll") for(int k=0;k<2;k++){ \
    D[ni][k] = *(const bf16x8*)(smem + (b)*49152 + 16384 + (np)*16384 + (wn*32 + ni*16 + ln15)*128 + colx[k]); }} } while(0)
#define QUAD_(mp, np, D) do { _Pragma("unroll") for (int mi=0;mi<2;mi++){ _Pragma("unroll") for(int ni=0;ni<2;ni++){ _Pragma("unroll") for(int k=0;k<2;k++){ \
    acc[(mp)*2+mi][(np)*2+ni] = __builtin_amdgcn_mfma_f32_16x16x32_bf16(afr[mi][k], D[ni][k], acc[(mp)*2+mi][(np)*2+ni], 0,0,0); }}} } while(0)

#define ITER(LAST, t) do { \
  /* P0: quad(m01,n01) of tile t */ \
  LDA_(0,0); LDB_(0,0,bfa); PH_STAGE_A(1,1,(t)+1); \
  SBAR; PRIO1; QUAD_(0,0,bfa); PRIO0; SBAR; \
  /* P1: quad(m01,n23) */ \
  LDB_(0,1,bfb); if(!(LAST)) PH_STAGE_A(0,0,(t)+2); \
  SBAR; PRIO1; QUAD_(0,1,bfb); PRIO0; SBAR; \
  /* P2: quad(m23,n23) */ \
  LDA_(0,1); if(!(LAST)) PH_STAGE_B(0,0,(t)+2); \
  SBAR; PRIO1; QUAD_(1,1,bfb); PRIO0; SBAR; \
  /* P3: quad(m23,n01), tile-boundary vmcnt */ \
  if(!(LAST)) PH_STAGE_B(0,1,(t)+2); \
  SBAR; PRIO1; QUAD_(1,0,bfa); PRIO0; \
  if(LAST) { VMCNT(0); } else { VMCNT(5); } SBAR; \
  /* P4: quad(m01,n01) of tile t+1 */ \
  LDA_(1,0); LDB_(1,0,bfa); if(!(LAST)) PH_STAGE_A(0,1,(t)+2); \
  SBAR; PRIO1; QUAD_(0,0,bfa); PRIO0; SBAR; \
  /* P5 */ \
  LDB_(1,1,bfb); if(!(LAST)) PH_STAGE_A(1,0,(t)+3); \
  SBAR; PRIO1; QUAD_(0,1,bfb); PRIO0; SBAR; \
  /* P6 */ \
  LDA_(1,1); if(!(LAST)) PH_STAGE_B(1,0,(t)+3); \
  SBAR; PRIO1; QUAD_(1,1,bfb); PRIO0; SBAR; \
  /* P7 */ \
  if(!(LAST)) PH_STAGE_B(1,1,(t)+3); \
  SBAR; PRIO1; QUAD_(1,0,bfa); PRIO0; \
  if(!(LAST)) { VMCNT(5); } SBAR; \
} while(0)

template<int KDIM, bool IS_FFN1>
__global__ __launch_bounds__(512, 2) void k_ffn8(
    const unsigned short* __restrict__ Abase,
    const unsigned short* __restrict__ Wb,
    const float* __restrict__ bias,
    const int* __restrict__ offs,
    const int* __restrict__ tok,
    const float* __restrict__ gate,
    unsigned short* __restrict__ hbuf,
    float* __restrict__ out)
{
    constexpr int NCOLS = IS_FFN1 ? HDIM : DDIM;
    constexpr int T = KDIM / 64;           // K-tiles (16 or 32, even)

    int e = blockIdx.y & 7, rt = blockIdx.y >> 3;
    int soff = offs[e];
    int n_e = offs[e + 1] - soff;
    int row0 = rt * 128;
    if (row0 >= n_e) return;               // uniform exit, before any barrier
    int ncol0 = blockIdx.x * 256;

    __shared__ __align__(16) char smem[98304];

    int tid = threadIdx.x;
    int w = tid >> 6, ln = tid & 63;
    int wm = w >> 2, wn = w & 3;
    int ln15 = ln & 15, g4 = ln >> 4;
    // swizzled ds_read 16B-chunk byte offsets for k-slice 0/1
    int colx[2];
#pragma unroll
    for (int k = 0; k < 2; k++) colx[k] = ((g4 + k * 4) ^ (ln15 & 7)) * 16;

    // ---- per-lane stage source pointers (swizzle pre-applied on global address) ----
    const unsigned short* aSrc[2];
#pragma unroll
    for (int c = 0; c < 2; c++) {
        int rho = w * 8 + (ln >> 3);                 // LDS row this lane fills
        int trow = (rho >> 5) * 64 + c * 32 + (rho & 31);
        int csrc = (ln & 7) ^ ((ln >> 3) & 7);
        int r = row0 + trow; if (r > n_e - 1) r = n_e - 1;
        size_t grow = IS_FFN1 ? (size_t)tok[soff + r] : (size_t)(soff + r);
        aSrc[c] = Abase + grow * KDIM + csrc * 8;
    }
    const unsigned short* Wexp = Wb + (size_t)e * NCOLS * KDIM;
    const unsigned short* bSrc[2][2];
#pragma unroll
    for (int c = 0; c < 2; c++)
#pragma unroll
        for (int i = 0; i < 2; i++) {
            int lam = i * 512 + tid;
            int rho = lam >> 3;
            int tcol = (rho >> 5) * 64 + c * 32 + (rho & 31);
            int csrc = (tid & 7) ^ (rho & 7);
            bSrc[c][i] = Wexp + (size_t)(ncol0 + tcol) * KDIM + csrc * 8;
        }

    f32x4 acc[4][4];
#pragma unroll
    for (int m = 0; m < 4; m++)
#pragma unroll
        for (int n = 0; n < 4; n++) acc[m][n] = (f32x4)0.f;

    bf16x8 afr[2][2], bfa[2][2], bfb[2][2];

    // ---- prologue: tile0 {A0,B0,B1,A1} + tile1 {A0,B0,B1} = 11 loads; keep 5 in flight
    PH_STAGE_A(0, 0, 0);
    PH_STAGE_B(0, 0, 0);
    PH_STAGE_B(0, 1, 0);
    PH_STAGE_A(0, 1, 0);
    PH_STAGE_A(1, 0, 1);
    PH_STAGE_B(1, 0, 1);
    PH_STAGE_B(1, 1, 1);
    VMCNT(5);
    SBAR;

    for (int t = 0; t + 2 < T; t += 2) ITER(false, t);
    ITER(true, T - 2);

    // ---- epilogue: C layout col=ln15 (n-side), row=g4*4+q (m-side) ----
    if (IS_FFN1) {
#pragma unroll
        for (int m = 0; m < 4; m++) {
#pragma unroll
            for (int q = 0; q < 4; q++) {
                int r = row0 + wm * 64 + m * 16 + g4 * 4 + q;
                if (r < n_e) {
#pragma unroll
                    for (int n = 0; n < 4; n++) {
                        int col = ncol0 + wn * 64 + n * 16 + ln15;
                        float v = acc[m][n][q] + bias[e * NCOLS + col];
                        float s = v / (1.f + __expf(-v));   // silu
                        hbuf[(size_t)(soff + r) * HDIM + col] = f2bf(s);
                    }
                }
            }
        }
    } else {
#pragma unroll
        for (int m = 0; m < 4; m++) {
#pragma unroll
            for (int q = 0; q < 4; q++) {
                int r = row0 + wm * 64 + m * 16 + g4 * 4 + q;
                if (r < n_e) {
                    int tk = tok[soff + r];
                    float gt = gate[soff + r];
#pragma unroll
                    for (int n = 0; n < 4; n++) {
                        int col = ncol0 + wn * 64 + n * 16 + ln15;
                        float v = gt * (acc[m][n][q] + bias[e * NCOLS + col]);
                        atomicAdd(&out[(size_t)tk * DDIM + col], v);
                    }
                }
            }
        }
    }
}

extern "C" void kernel_launch(void* const* d_in, const int* in_sizes, int n_in,
                              void* d_out, int out_size, void* d_ws, size_t ws_size,
                              hipStream_t stream)
{
    const float* x  = (const float*)d_in[0];
    const float* gw = (const float*)d_in[1];
    const float* w1 = (const float*)d_in[2];
    const float* b1 = (const float*)d_in[3];
    const float* w2 = (const float*)d_in[4];
    const float* b2 = (const float*)d_in[5];
    float* out = (float*)d_out;

    char* ws = (char*)d_ws;
    size_t off = 0;
    auto alloc = [&](size_t bytes) {
        char* p = ws + off; off += (bytes + 255) & ~(size_t)255; return p;
    };
    unsigned short* xb  = (unsigned short*)alloc((size_t)NTOK * DDIM * 2);           // 8.4 MB
    unsigned short* w1b = (unsigned short*)alloc((size_t)NEXP * HDIM * DDIM * 2);    // 33.5 MB
    unsigned short* w2b = (unsigned short*)alloc((size_t)NEXP * DDIM * HDIM * 2);    // 33.5 MB
    unsigned short* hb  = (unsigned short*)alloc((size_t)NTOK * TOPK * HDIM * 2);    // 33.5 MB
    int*   tok  = (int*)alloc(NTOK * TOPK * 4);
    float* gate = (float*)alloc(NTOK * TOPK * 4);
    int*   topi = (int*)alloc(NTOK * TOPK * 4);
    float* topg = (float*)alloc(NTOK * TOPK * 4);
    int*   ctrl = (int*)alloc(256);   // ints: [0..7]=cnt, [16..24]=offs, [32..39]=fill

    int* cnt  = ctrl;
    int* offs = ctrl + 16;
    int* fill = ctrl + 32;

    hipMemsetAsync(ctrl, 0, 256, stream);
    hipMemsetAsync(d_out, 0, (size_t)out_size * sizeof(float), stream);

    k_gate<<<NTOK / 4, 256, 0, stream>>>(x, gw, xb, cnt, topi, topg);
    k_scan<<<1, 64, 0, stream>>>(cnt, offs, out + (size_t)NTOK * DDIM);
    k_scatter<<<(NTOK * TOPK) / 256, 256, 0, stream>>>(topi, topg, offs, fill, tok, gate);
    k_conv<<<2048, 256, 0, stream>>>((const float4*)w1, (const float4*)w2,
                                     (ushort4*)w1b, (ushort4*)w2b);
    // y = rowtile*8 + e : active blocks lead the dispatch order, balanced across experts
    k_ffn8<DDIM, true ><<<dim3(HDIM / 256, (NTOK / 128) * NEXP), 512, 0, stream>>>(
        xb, w1b, b1, offs, tok, gate, hb, out);
    k_ffn8<HDIM, false><<<dim3(DDIM / 256, (NTOK / 128) * NEXP), 512, 0, stream>>>(
        hb, w2b, b2, offs, tok, gate, hb, out);
}